// Round 9
// baseline (336.751 us; speedup 1.0000x reference)
//
#include <hip/hip_runtime.h>
#include <math.h>

#define HEADS 16
#define HEAD_DIM 64
#define HIDDEN 1024
#define NQKVFF 7168
#define VFF 5120
#define SEQ 2048
#define MROWS 4096

typedef unsigned short u16;
typedef __attribute__((ext_vector_type(8))) short bf16x8;
typedef __attribute__((ext_vector_type(4))) float f32x4;
typedef __attribute__((address_space(1))) void gas_void;
typedef __attribute__((address_space(3))) void las_void;

__device__ inline u16 f2bf(float f) {
    union { float f; unsigned u; } v; v.f = f;
    unsigned r = v.u + 0x7FFFu + ((v.u >> 16) & 1u);
    return (u16)(r >> 16);
}
__device__ inline float bf2f(u16 h) {
    union { unsigned u; float f; } v; v.u = ((unsigned)h) << 16;
    return v.f;
}

// ---------------- LayerNorm: fp32 [4096][1024] -> bf16 [4096][1024] ----------
__global__ __launch_bounds__(256) void ln_kernel(const float* __restrict__ x,
        const float* __restrict__ w, const float* __restrict__ b,
        u16* __restrict__ xn) {
    int row = blockIdx.x;
    int tid = threadIdx.x;
    const float* xr = x + (size_t)row * HIDDEN;
    float4 v = ((const float4*)xr)[tid];
    float s = v.x + v.y + v.z + v.w;
    float sq = v.x * v.x + v.y * v.y + v.z * v.z + v.w * v.w;
    for (int off = 32; off > 0; off >>= 1) {
        s += __shfl_down(s, off, 64);
        sq += __shfl_down(sq, off, 64);
    }
    __shared__ float ls[4], lsq[4];
    int wid = tid >> 6, lane = tid & 63;
    if (lane == 0) { ls[wid] = s; lsq[wid] = sq; }
    __syncthreads();
    float ts = ls[0] + ls[1] + ls[2] + ls[3];
    float tsq = lsq[0] + lsq[1] + lsq[2] + lsq[3];
    float mu = ts * (1.0f / HIDDEN);
    float var = tsq * (1.0f / HIDDEN) - mu * mu;
    float rstd = rsqrtf(var + 1e-5f);
    float4 wv = ((const float4*)w)[tid];
    float4 bv = ((const float4*)b)[tid];
    ushort4 o;
    o.x = f2bf((v.x - mu) * rstd * wv.x + bv.x);
    o.y = f2bf((v.y - mu) * rstd * wv.y + bv.y);
    o.z = f2bf((v.z - mu) * rstd * wv.z + bv.z);
    o.w = f2bf((v.w - mu) * rstd * wv.w + bv.w);
    ((ushort4*)(xn + (size_t)row * HIDDEN))[tid] = o;
}

// ---------- Transpose + cast: fp32 in[R][C] -> bf16 out[C][R] ----------------
__global__ __launch_bounds__(256) void transpose_f2b(const float* __restrict__ in,
        u16* __restrict__ out, int R, int C) {
    __shared__ u16 tile[32][33];
    int c0 = blockIdx.x * 32, r0 = blockIdx.y * 32;
    int tx = threadIdx.x & 31, ty = threadIdx.x >> 5;
#pragma unroll
    for (int k = 0; k < 4; k++)
        tile[ty + k * 8][tx] = f2bf(in[(size_t)(r0 + ty + k * 8) * C + c0 + tx]);
    __syncthreads();
#pragma unroll
    for (int k = 0; k < 4; k++)
        out[(size_t)(c0 + ty + k * 8) * R + r0 + tx] = tile[tx][ty + k * 8];
}

// ------- 128x128 bf16 MFMA GEMM core, DOUBLE-BUFFERED 2-phase (T3-min) -------
// (R7-verified: stage t+1 issued before compute of t; one barrier per K-step;
// XOR swizzle conflict-free; reads buf[cur], writes buf[nxt] — disjoint.)
// R8 lesson: XCD-rect blockIdx swizzle REGRESSED (FETCH 73->80 MB, +9 µs) —
// the assumed bid%8->XCD mapping doesn't hold for this launch shape.  Plain
// blockIdx mapping restored; 664 TF here IS the documented 2-phase ceiling
// (m230/m233: 607-682 TF) — next GEMM lever is the 8-phase 256^2 template.
__device__ inline void gemm_core_128(const u16* __restrict__ A, int lda,
                                     const u16* __restrict__ BT, int ldb,
                                     int Klen, int bm, int bn, f32x4 acc[4][4],
                                     u16* lds) {
    const int tid = threadIdx.x;
    const int wid = tid >> 6;
    const int lane = tid & 63;
    const int quad = lane >> 4;
    const int cc = lane & 15;
    const int wm = (wid >> 1) * 64;
    const int wn = (wid & 1) * 64;
#pragma unroll
    for (int i = 0; i < 4; i++)
#pragma unroll
        for (int j = 0; j < 4; j++)
#pragma unroll
            for (int r = 0; r < 4; r++) acc[i][j][r] = 0.0f;

    const int row = tid >> 2;                       // 0..63
    const int gch = ((tid & 3) ^ ((row >> 1) & 3)) * 8;   // swizzled global chunk
    const int slot = (quad ^ ((cc >> 1) & 3)) * 8;        // swizzled read slot
    const int lofs = (tid & 192) * 8;               // wave's 512-u16 slice base

    u16* cur = lds;
    u16* nxt = lds + 8192;

    // prologue: stage tile 0
#pragma unroll
    for (int I = 0; I < 2; I++) {
        int r128 = I * 64 + row;
        const u16* ga = A + (size_t)(bm + r128) * lda + gch;
        __builtin_amdgcn_global_load_lds((gas_void*)ga,
                (las_void*)(cur + I * 2048 + lofs), 16, 0, 0);
        const u16* gb = BT + (size_t)(bn + r128) * ldb + gch;
        __builtin_amdgcn_global_load_lds((gas_void*)gb,
                (las_void*)(cur + 4096 + I * 2048 + lofs), 16, 0, 0);
    }
    __syncthreads();

    for (int k0 = 0; k0 < Klen; k0 += 32) {
        const bool more = (k0 + 32 < Klen);
        if (more) {
            // issue next tile's staging loads FIRST (overlap with compute)
#pragma unroll
            for (int I = 0; I < 2; I++) {
                int r128 = I * 64 + row;
                const u16* ga = A + (size_t)(bm + r128) * lda + k0 + 32 + gch;
                __builtin_amdgcn_global_load_lds((gas_void*)ga,
                        (las_void*)(nxt + I * 2048 + lofs), 16, 0, 0);
                const u16* gb = BT + (size_t)(bn + r128) * ldb + k0 + 32 + gch;
                __builtin_amdgcn_global_load_lds((gas_void*)gb,
                        (las_void*)(nxt + 4096 + I * 2048 + lofs), 16, 0, 0);
            }
        }
        bf16x8 af[4], bfr[4];
#pragma unroll
        for (int t = 0; t < 4; t++) {
            af[t]  = *(const bf16x8*)(cur + (wm + t * 16 + cc) * 32 + slot);
            bfr[t] = *(const bf16x8*)(cur + 4096 + (wn + t * 16 + cc) * 32 + slot);
        }
        __builtin_amdgcn_s_setprio(1);
#pragma unroll
        for (int i = 0; i < 4; i++)
#pragma unroll
            for (int j = 0; j < 4; j++)
                acc[i][j] = __builtin_amdgcn_mfma_f32_16x16x32_bf16(af[i], bfr[j], acc[i][j], 0, 0, 0);
        __builtin_amdgcn_s_setprio(0);
        if (more) __syncthreads();   // drains vmcnt(0): next tile fully in LDS
        u16* tmp = cur; cur = nxt; nxt = tmp;
    }
}

// exp2-based tanh GELU (max |err| vs exact ~3e-3, well under threshold)
__device__ inline float gelu_f(float v) {
    float u = v * (v * v * 0.044715f + 1.0f) * 0.7978845608028654f;
    u = fminf(u, 15.0f);                       // saturate (avoid inf/inf)
    float e = exp2f(u * 2.8853900817779268f);  // e^(2u)
    return v * (e / (e + 1.0f));               // v * 0.5*(1+tanh(u))
}

// GEMM1 FUSED (128x128, 2-phase dbuf): xn @ W_in, epilogue by bn:
//   bn <  2048: RoPE + scatter into MFMA-fragment-packed qkb
//   bn <  3072: pack into MFMA-fragment-packed vtb
//   bn >= 3072: gelu -> a2[:, 1024:]
// (R4-verified epilogues, R3-verified packed layouts.)
__global__ __launch_bounds__(256) void gemm1(const u16* __restrict__ xn,
        const u16* __restrict__ WinT, u16* __restrict__ qkb,
        u16* __restrict__ vtb, u16* __restrict__ a2) {
    __shared__ u16 lds[2 * 8192];
    int bm = blockIdx.x * 128, bn = blockIdx.y * 128;
    f32x4 acc[4][4];
    gemm_core_128(xn, HIDDEN, WinT, HIDDEN, HIDDEN, bm, bn, acc, lds);
    const int tid = threadIdx.x, wid = tid >> 6, lane = tid & 63;
    const int quad = lane >> 4, cc = lane & 15;
    const int wm = (wid >> 1) * 64, wn = (wid & 1) * 64;
    const int m0 = bm + wm;             // wave's first output row (64-aligned)
    const int b = m0 >> 11;             // batch index (wave-uniform)

    if (bn >= 3072) {
        // ---- FF: gelu -> a2 cols 1024..5119 ----
#pragma unroll
        for (int i = 0; i < 4; i++)
#pragma unroll
            for (int j = 0; j < 4; j++)
#pragma unroll
                for (int r = 0; r < 4; r++) {
                    int m = m0 + i * 16 + quad * 4 + r;
                    int n = bn + wn + j * 16 + cc;
                    a2[(size_t)m * VFF + (n - 2048)] = f2bf(gelu_f(acc[i][j][r]));
                }
    } else if (bn >= 2048) {
        // ---- V: pack to vtb[bh][key>>5][d>>4][((key&31)>>3)*16 + (d&15)][key&7]
        int hh = ((bn - 2048 + wn) >> 6) & 15;           // wave-uniform head
        u16* dst = vtb + (size_t)(b * 16 + hh) * (HEAD_DIM * SEQ);
#pragma unroll
        for (int i = 0; i < 4; i++) {
            int key0 = (m0 + i * 16 + quad * 4) & 2047;  // r=0..3 consecutive
            size_t ob = (size_t)(key0 >> 5) * 2048 +
                        (((key0 & 31) >> 3) * 16 + cc) * 8 + (key0 & 7);
#pragma unroll
            for (int jf = 0; jf < 4; jf++) {             // d = jf*16 + cc
                ushort4 o;
                o.x = f2bf(acc[i][jf][0]);
                o.y = f2bf(acc[i][jf][1]);
                o.z = f2bf(acc[i][jf][2]);
                o.w = f2bf(acc[i][jf][3]);
                *(ushort4*)(dst + ob + jf * 512) = o;
            }
        }
    } else {
        // ---- Q/K: RoPE + pack to qkb (same formulas as old rope_kernel) ----
        int t = bn >> 10;                                 // 0=q, 1=k (uniform)
        int hh = ((bn + wn) >> 6) & 15;                   // wave-uniform head
        u16* base = qkb + (size_t)(t * 32 + b * 16 + hh) * (SEQ * HEAD_DIM);
        float scale = t ? 1.0f : 0.18033688011112043f;    // 0.125*log2(e) on q
        float f0 = expf(cc * -0.28782313662425572f);      // 10000^(-d1/32)
        float f1 = expf((16 + cc) * -0.28782313662425572f);
        const int o0 = ((cc >> 3) * 16) * 8 + (cc & 7);          // d1 = cc
        const int o1 = ((2 + (cc >> 3)) * 16) * 8 + (cc & 7);    // d1 = 16+cc
#pragma unroll
        for (int i = 0; i < 4; i++)
#pragma unroll
            for (int r = 0; r < 4; r++) {
                int pos = (m0 + i * 16 + quad * 4 + r) & 2047;
                int ob = (pos >> 4) * 1024 + (pos & 15) * 8;
                float s_, c_;
                __sincosf(pos * f0, &s_, &c_);
                float x1 = acc[i][0][r], x2 = acc[i][2][r];
                base[ob + o0]       = f2bf((x1 * c_ - x2 * s_) * scale);
                base[ob + o0 + 512] = f2bf((x2 * c_ + x1 * s_) * scale);
                __sincosf(pos * f1, &s_, &c_);
                x1 = acc[i][1][r]; x2 = acc[i][3][r];
                base[ob + o1]       = f2bf((x1 * c_ - x2 * s_) * scale);
                base[ob + o1 + 512] = f2bf((x2 * c_ + x1 * s_) * scale);
            }
    }
}

// GEMM2 split-K (2-phase dbuf): a2[4096][5120] @ W_out -> out via atomicAdd.
// reduce2 eliminated: out is zeroed by hipMemsetAsync, each split atomicAdds
// its partial.  With exactly TWO contributions per element this is bitwise
// order-independent (IEEE a+b == b+a; 0+v == v), so results are identical to
// the old p0+p1 reduce.  Saves the 48 MB reduce2 round-trip + one dispatch.
__global__ __launch_bounds__(256) void gemm2(const u16* __restrict__ a2,
        const u16* __restrict__ WoutT, float* __restrict__ out) {
    __shared__ u16 lds[2 * 8192];
    int bm = blockIdx.x * 128, bn = blockIdx.y * 128;
    int split = blockIdx.z;
    f32x4 acc[4][4];
    gemm_core_128(a2 + split * 2560, VFF, WoutT + split * 2560, VFF, 2560,
                  bm, bn, acc, lds);
    const int tid = threadIdx.x, wid = tid >> 6, lane = tid & 63;
    const int quad = lane >> 4, cc = lane & 15;
    const int wm = (wid >> 1) * 64, wn = (wid & 1) * 64;
#pragma unroll
    for (int i = 0; i < 4; i++)
#pragma unroll
        for (int j = 0; j < 4; j++)
#pragma unroll
            for (int r = 0; r < 4; r++) {
                int m = bm + wm + i * 16 + quad * 4 + r;
                int n = bn + wn + j * 16 + cc;
                atomicAdd(&out[(size_t)m * HIDDEN + n], acc[i][j][r]);
            }
}

// ------- Flash attention, causal, MFMA — FIXED-OFFSET softmax ---------------
// Q/K/V are pre-packed in MFMA fragment order (1KB blob per 16-row x 32-dim
// fragment, lane-major), so every fragment load is ONE contiguous 1KB wave
// load instead of a 16-segment row gather (R2 diagnosis: 256 divergent 64B
// transactions per chunk per wave -> MSHR/TA serialization, 73% stall).
// bh packing already gives each XCD a 4-head (2 MB) L2-resident K/V set.
__global__ __launch_bounds__(256) void attn_kernel(const u16* __restrict__ qk,
        const u16* __restrict__ vt, u16* __restrict__ a2) {
    const int id  = blockIdx.x;
    const int bh  = (id & 7) * 4 + ((id >> 3) & 3);
    const int bx  = id >> 5;
    const int tid = threadIdx.x;
    const int wid = tid >> 6;
    const int lane = tid & 63;
    const int quad = lane >> 4;
    const int cc = lane & 15;
    const int slot = wid >> 1;            // 0: tile bx, 1: tile 127-bx
    const int parity = wid & 1;
    const int tile = slot ? (127 - bx) : bx;
    const int q0 = tile * 16;

    const u16* Qp = qk + (size_t)bh * (SEQ * HEAD_DIM);
    const u16* Kp = qk + (size_t)(32 + bh) * (SEQ * HEAD_DIM);
    const u16* VP = vt + (size_t)bh * (HEAD_DIM * SEQ);

    __shared__ u16 Pbuf[4][16 * 72];      // per-wave P [q=16][key=64], stride 72
    __shared__ float obuf[2][64 * 17];    // merge: per-slot O^T (lane-major, pad 17)
    __shared__ float lbuf[2][16];         // merge: per-slot partial l per q
    u16* P = Pbuf[wid];

    const int bb = bh >> 4, hh = bh & 15;
    const int qcol = q0 + cc;

    // Q fragments from packed layout: one contiguous 1KB load per fragment
    bf16x8 qa0 = *(const bf16x8*)(Qp + (q0 >> 4) * 1024 + lane * 8);
    bf16x8 qa1 = *(const bf16x8*)(Qp + (q0 >> 4) * 1024 + 512 + lane * 8);

    float ps = 0.0f;                      // per-lane partial row-sum (this parity)
    f32x4 ot[4];                          // O^T: ot[mt][r] = O^T[d=mt*16+quad*4+r][q=cc]
#pragma unroll
    for (int mt = 0; mt < 4; mt++)
#pragma unroll
        for (int r = 0; r < 4; r++) ot[mt][r] = 0.0f;

    for (int kb = parity * 64; kb < q0 + 16; kb += 128) {
        const bool diag = (kb + 64 > q0);  // only the diagonal chunk needs masking
        // S^T = K Q^T - 32 (offset rides the accumulator init)
        f32x4 s[4];
        __builtin_amdgcn_s_setprio(1);
#pragma unroll
        for (int c = 0; c < 4; c++) {
            s[c][0] = -32.0f; s[c][1] = -32.0f; s[c][2] = -32.0f; s[c][3] = -32.0f;
            const u16* kblob = Kp + ((kb >> 4) + c) * 1024 + lane * 8;
            bf16x8 ka0 = *(const bf16x8*)(kblob);
            bf16x8 ka1 = *(const bf16x8*)(kblob + 512);
            s[c] = __builtin_amdgcn_mfma_f32_16x16x32_bf16(ka0, qa0, s[c], 0, 0, 0);
            s[c] = __builtin_amdgcn_mfma_f32_16x16x32_bf16(ka1, qa1, s[c], 0, 0, 0);
        }
        __builtin_amdgcn_s_setprio(0);
        // prefetch V^T for this chunk (overlaps the exp/stage phase)
        bf16x8 vf[2][4];
#pragma unroll
        for (int kc = 0; kc < 2; kc++)
#pragma unroll
            for (int mt = 0; mt < 4; mt++)
                vf[kc][mt] = *(const bf16x8*)(VP + ((kb >> 5) + kc) * 2048 + mt * 512 + lane * 8);
        // causal mask (diagonal chunk only; off-diag chunks are fully valid)
        if (diag) {
#pragma unroll
            for (int c = 0; c < 4; c++)
#pragma unroll
                for (int r = 0; r < 4; r++) {
                    int key = kb + c * 16 + quad * 4 + r;
                    s[c][r] = (key <= qcol) ? s[c][r] : -10000.0f;
                }
        }
        // P = exp2(s); local l accumulation (no cross-lane ops); cvt_pk pack
#pragma unroll
        for (int c = 0; c < 4; c++) {
            float p0v = exp2f(s[c][0]); ps += p0v;
            float p1v = exp2f(s[c][1]); ps += p1v;
            float p2v = exp2f(s[c][2]); ps += p2v;
            float p3v = exp2f(s[c][3]); ps += p3v;
            unsigned r0, r1;
            asm("v_cvt_pk_bf16_f32 %0, %1, %2" : "=v"(r0) : "v"(p0v), "v"(p1v));
            asm("v_cvt_pk_bf16_f32 %0, %1, %2" : "=v"(r1) : "v"(p2v), "v"(p3v));
            uint2 pk; pk.x = r0; pk.y = r1;
            *(uint2*)(P + cc * 72 + c * 16 + quad * 4) = pk;
        }
        asm volatile("s_waitcnt lgkmcnt(0)" ::: "memory");
        // O^T += V^T P^T
        __builtin_amdgcn_s_setprio(1);
#pragma unroll
        for (int kc = 0; kc < 2; kc++) {
            bf16x8 pb = *(const bf16x8*)(P + cc * 72 + kc * 32 + quad * 8);
#pragma unroll
            for (int mt = 0; mt < 4; mt++)
                ot[mt] = __builtin_amdgcn_mfma_f32_16x16x32_bf16(vf[kc][mt], pb, ot[mt], 0, 0, 0);
        }
        __builtin_amdgcn_s_setprio(0);
    }

    // ONE cross-lane l reduction (quads of same q-column)
    ps += __shfl_xor(ps, 16, 64);
    ps += __shfl_xor(ps, 32, 64);

    // ---- merge the two parity waves of each tile (plain add; no max) ----
    if (parity == 1) {
        if (quad == 0) lbuf[slot][cc] = ps;
        float* ob = obuf[slot] + lane * 17;
#pragma unroll
        for (int mt = 0; mt < 4; mt++)
#pragma unroll
            for (int r = 0; r < 4; r++) ob[mt * 4 + r] = ot[mt][r];
    }
    __syncthreads();
    if (parity == 0) {
        float l = ps + lbuf[slot][cc];
        float rl = 1.0f / l;
        const float* ob = obuf[slot] + lane * 17;
        u16* dst = a2 + ((size_t)(bb * SEQ + q0 + cc)) * VFF + hh * 64;
#pragma unroll
        for (int mt = 0; mt < 4; mt++) {
            ushort4 o;
            o.x = f2bf((ot[mt][0] + ob[mt * 4 + 0]) * rl);
            o.y = f2bf((ot[mt][1] + ob[mt * 4 + 1]) * rl);
            o.z = f2bf((ot[mt][2] + ob[mt * 4 + 2]) * rl);
            o.w = f2bf((ot[mt][3] + ob[mt * 4 + 3]) * rl);
            *(ushort4*)(dst + mt * 16 + quad * 4) = o;
        }
    }
}

extern "C" void kernel_launch(void* const* d_in, const int* in_sizes, int n_in,
                              void* d_out, int out_size, void* d_ws, size_t ws_size,
                              hipStream_t stream) {
    const float* x     = (const float*)d_in[0];
    const float* ln_w  = (const float*)d_in[1];
    const float* ln_b  = (const float*)d_in[2];
    const float* W_in  = (const float*)d_in[3];
    const float* W_out = (const float*)d_in[4];
    float* out = (float*)d_out;
    char* ws = (char*)d_ws;
    // Layout (peak 100663296 B):
    //   xn    @ 0         (8 MB)   dead after gemm1
    //   WinT  @ 8388608   (14 MB)  dead after gemm1
    //   qkb   @ 23068672  (16 MB)  gemm1 -> attn
    //   vtb   @ 39845888  (8 MB)   gemm1 -> attn
    //   WoutT @ 48234496  (10 MB)  -> gemm2
    //   a2    @ 58720256  (40 MB)  gemm1/attn -> gemm2
    u16* xn    = (u16*)(ws);
    u16* WinT  = (u16*)(ws + 8388608);
    u16* qkb   = (u16*)(ws + 23068672);
    u16* vtb   = (u16*)(ws + 39845888);
    u16* WoutT = (u16*)(ws + 48234496);
    u16* a2    = (u16*)(ws + 58720256);

    hipMemsetAsync(out, 0, (size_t)MROWS * HIDDEN * sizeof(float), stream);
    ln_kernel<<<dim3(MROWS), dim3(256), 0, stream>>>(x, ln_w, ln_b, xn);
    transpose_f2b<<<dim3(NQKVFF / 32, HIDDEN / 32), dim3(256), 0, stream>>>(W_in, WinT, HIDDEN, NQKVFF);
    transpose_f2b<<<dim3(HIDDEN / 32, VFF / 32), dim3(256), 0, stream>>>(W_out, WoutT, VFF, HIDDEN);
    gemm1<<<dim3(MROWS / 128, NQKVFF / 128), dim3(256), 0, stream>>>(xn, WinT, qkb, vtb, a2);
    attn_kernel<<<dim3(2048), dim3(256), 0, stream>>>(qkb, vtb, a2);
    gemm2<<<dim3(MROWS / 128, HIDDEN / 128, 2), dim3(256), 0, stream>>>(a2, WoutT, out);
}

// Round 10
// 313.006 us; speedup vs baseline: 1.0759x; 1.0759x over previous
//
#include <hip/hip_runtime.h>
#include <math.h>

#define HEADS 16
#define HEAD_DIM 64
#define HIDDEN 1024
#define NQKVFF 7168
#define VFF 5120
#define SEQ 2048
#define MROWS 4096

typedef unsigned short u16;
typedef __attribute__((ext_vector_type(8))) short bf16x8;
typedef __attribute__((ext_vector_type(4))) float f32x4;
typedef __attribute__((address_space(1))) void gas_void;
typedef __attribute__((address_space(3))) void las_void;

__device__ inline u16 f2bf(float f) {
    union { float f; unsigned u; } v; v.f = f;
    unsigned r = v.u + 0x7FFFu + ((v.u >> 16) & 1u);
    return (u16)(r >> 16);
}
__device__ inline float bf2f(u16 h) {
    union { unsigned u; float f; } v; v.u = ((unsigned)h) << 16;
    return v.f;
}

// ---------------- LayerNorm: fp32 [4096][1024] -> bf16 [4096][1024] ----------
__global__ __launch_bounds__(256) void ln_kernel(const float* __restrict__ x,
        const float* __restrict__ w, const float* __restrict__ b,
        u16* __restrict__ xn) {
    int row = blockIdx.x;
    int tid = threadIdx.x;
    const float* xr = x + (size_t)row * HIDDEN;
    float4 v = ((const float4*)xr)[tid];
    float s = v.x + v.y + v.z + v.w;
    float sq = v.x * v.x + v.y * v.y + v.z * v.z + v.w * v.w;
    for (int off = 32; off > 0; off >>= 1) {
        s += __shfl_down(s, off, 64);
        sq += __shfl_down(sq, off, 64);
    }
    __shared__ float ls[4], lsq[4];
    int wid = tid >> 6, lane = tid & 63;
    if (lane == 0) { ls[wid] = s; lsq[wid] = sq; }
    __syncthreads();
    float ts = ls[0] + ls[1] + ls[2] + ls[3];
    float tsq = lsq[0] + lsq[1] + lsq[2] + lsq[3];
    float mu = ts * (1.0f / HIDDEN);
    float var = tsq * (1.0f / HIDDEN) - mu * mu;
    float rstd = rsqrtf(var + 1e-5f);
    float4 wv = ((const float4*)w)[tid];
    float4 bv = ((const float4*)b)[tid];
    ushort4 o;
    o.x = f2bf((v.x - mu) * rstd * wv.x + bv.x);
    o.y = f2bf((v.y - mu) * rstd * wv.y + bv.y);
    o.z = f2bf((v.z - mu) * rstd * wv.z + bv.z);
    o.w = f2bf((v.w - mu) * rstd * wv.w + bv.w);
    ((ushort4*)(xn + (size_t)row * HIDDEN))[tid] = o;
}

// ---------- Transpose + cast: fp32 in[R][C] -> bf16 out[C][R] ----------------
__global__ __launch_bounds__(256) void transpose_f2b(const float* __restrict__ in,
        u16* __restrict__ out, int R, int C) {
    __shared__ u16 tile[32][33];
    int c0 = blockIdx.x * 32, r0 = blockIdx.y * 32;
    int tx = threadIdx.x & 31, ty = threadIdx.x >> 5;
#pragma unroll
    for (int k = 0; k < 4; k++)
        tile[ty + k * 8][tx] = f2bf(in[(size_t)(r0 + ty + k * 8) * C + c0 + tx]);
    __syncthreads();
#pragma unroll
    for (int k = 0; k < 4; k++)
        out[(size_t)(c0 + ty + k * 8) * R + r0 + tx] = tile[tx][ty + k * 8];
}

// ------- 128x128 bf16 MFMA GEMM core, DOUBLE-BUFFERED 2-phase (T3-min) -------
// (R7-verified: stage t+1 issued before compute of t; one barrier per K-step;
// XOR swizzle conflict-free; reads buf[cur], writes buf[nxt] — disjoint.)
// R8 lesson: XCD-rect blockIdx swizzle regressed (default dispatch already has
// chunked XCD locality; bid%8 is NOT the XCD id).  R9 lesson: split-K via fp32
// atomicAdd regressed ~30 µs (8.4M scattered atomics >> 48 MB reduce pass).
// 664 TF here IS the documented 2-phase ceiling (m230/m233: 607-682 TF).
__device__ inline void gemm_core_128(const u16* __restrict__ A, int lda,
                                     const u16* __restrict__ BT, int ldb,
                                     int Klen, int bm, int bn, f32x4 acc[4][4],
                                     u16* lds) {
    const int tid = threadIdx.x;
    const int wid = tid >> 6;
    const int lane = tid & 63;
    const int quad = lane >> 4;
    const int cc = lane & 15;
    const int wm = (wid >> 1) * 64;
    const int wn = (wid & 1) * 64;
#pragma unroll
    for (int i = 0; i < 4; i++)
#pragma unroll
        for (int j = 0; j < 4; j++)
#pragma unroll
            for (int r = 0; r < 4; r++) acc[i][j][r] = 0.0f;

    const int row = tid >> 2;                       // 0..63
    const int gch = ((tid & 3) ^ ((row >> 1) & 3)) * 8;   // swizzled global chunk
    const int slot = (quad ^ ((cc >> 1) & 3)) * 8;        // swizzled read slot
    const int lofs = (tid & 192) * 8;               // wave's 512-u16 slice base

    u16* cur = lds;
    u16* nxt = lds + 8192;

    // prologue: stage tile 0
#pragma unroll
    for (int I = 0; I < 2; I++) {
        int r128 = I * 64 + row;
        const u16* ga = A + (size_t)(bm + r128) * lda + gch;
        __builtin_amdgcn_global_load_lds((gas_void*)ga,
                (las_void*)(cur + I * 2048 + lofs), 16, 0, 0);
        const u16* gb = BT + (size_t)(bn + r128) * ldb + gch;
        __builtin_amdgcn_global_load_lds((gas_void*)gb,
                (las_void*)(cur + 4096 + I * 2048 + lofs), 16, 0, 0);
    }
    __syncthreads();

    for (int k0 = 0; k0 < Klen; k0 += 32) {
        const bool more = (k0 + 32 < Klen);
        if (more) {
            // issue next tile's staging loads FIRST (overlap with compute)
#pragma unroll
            for (int I = 0; I < 2; I++) {
                int r128 = I * 64 + row;
                const u16* ga = A + (size_t)(bm + r128) * lda + k0 + 32 + gch;
                __builtin_amdgcn_global_load_lds((gas_void*)ga,
                        (las_void*)(nxt + I * 2048 + lofs), 16, 0, 0);
                const u16* gb = BT + (size_t)(bn + r128) * ldb + k0 + 32 + gch;
                __builtin_amdgcn_global_load_lds((gas_void*)gb,
                        (las_void*)(nxt + 4096 + I * 2048 + lofs), 16, 0, 0);
            }
        }
        bf16x8 af[4], bfr[4];
#pragma unroll
        for (int t = 0; t < 4; t++) {
            af[t]  = *(const bf16x8*)(cur + (wm + t * 16 + cc) * 32 + slot);
            bfr[t] = *(const bf16x8*)(cur + 4096 + (wn + t * 16 + cc) * 32 + slot);
        }
        __builtin_amdgcn_s_setprio(1);
#pragma unroll
        for (int i = 0; i < 4; i++)
#pragma unroll
            for (int j = 0; j < 4; j++)
                acc[i][j] = __builtin_amdgcn_mfma_f32_16x16x32_bf16(af[i], bfr[j], acc[i][j], 0, 0, 0);
        __builtin_amdgcn_s_setprio(0);
        if (more) __syncthreads();   // drains vmcnt(0): next tile fully in LDS
        u16* tmp = cur; cur = nxt; nxt = tmp;
    }
}

// exp2-based tanh GELU (max |err| vs exact ~3e-3, well under threshold)
__device__ inline float gelu_f(float v) {
    float u = v * (v * v * 0.044715f + 1.0f) * 0.7978845608028654f;
    u = fminf(u, 15.0f);                       // saturate (avoid inf/inf)
    float e = exp2f(u * 2.8853900817779268f);  // e^(2u)
    return v * (e / (e + 1.0f));               // v * 0.5*(1+tanh(u))
}

// GEMM1 FUSED (128x128, 2-phase dbuf): xn @ W_in, epilogue by bn:
//   bn <  2048: RoPE + scatter into MFMA-fragment-packed qkb
//   bn <  3072: pack into MFMA-fragment-packed vtb
//   bn >= 3072: gelu -> a2[:, 1024:]
// (R4-verified epilogues, R3-verified packed layouts.)
__global__ __launch_bounds__(256) void gemm1(const u16* __restrict__ xn,
        const u16* __restrict__ WinT, u16* __restrict__ qkb,
        u16* __restrict__ vtb, u16* __restrict__ a2) {
    __shared__ u16 lds[2 * 8192];
    int bm = blockIdx.x * 128, bn = blockIdx.y * 128;
    f32x4 acc[4][4];
    gemm_core_128(xn, HIDDEN, WinT, HIDDEN, HIDDEN, bm, bn, acc, lds);
    const int tid = threadIdx.x, wid = tid >> 6, lane = tid & 63;
    const int quad = lane >> 4, cc = lane & 15;
    const int wm = (wid >> 1) * 64, wn = (wid & 1) * 64;
    const int m0 = bm + wm;             // wave's first output row (64-aligned)
    const int b = m0 >> 11;             // batch index (wave-uniform)

    if (bn >= 3072) {
        // ---- FF: gelu -> a2 cols 1024..5119 ----
#pragma unroll
        for (int i = 0; i < 4; i++)
#pragma unroll
            for (int j = 0; j < 4; j++)
#pragma unroll
                for (int r = 0; r < 4; r++) {
                    int m = m0 + i * 16 + quad * 4 + r;
                    int n = bn + wn + j * 16 + cc;
                    a2[(size_t)m * VFF + (n - 2048)] = f2bf(gelu_f(acc[i][j][r]));
                }
    } else if (bn >= 2048) {
        // ---- V: pack to vtb[bh][key>>5][d>>4][((key&31)>>3)*16 + (d&15)][key&7]
        int hh = ((bn - 2048 + wn) >> 6) & 15;           // wave-uniform head
        u16* dst = vtb + (size_t)(b * 16 + hh) * (HEAD_DIM * SEQ);
#pragma unroll
        for (int i = 0; i < 4; i++) {
            int key0 = (m0 + i * 16 + quad * 4) & 2047;  // r=0..3 consecutive
            size_t ob = (size_t)(key0 >> 5) * 2048 +
                        (((key0 & 31) >> 3) * 16 + cc) * 8 + (key0 & 7);
#pragma unroll
            for (int jf = 0; jf < 4; jf++) {             // d = jf*16 + cc
                ushort4 o;
                o.x = f2bf(acc[i][jf][0]);
                o.y = f2bf(acc[i][jf][1]);
                o.z = f2bf(acc[i][jf][2]);
                o.w = f2bf(acc[i][jf][3]);
                *(ushort4*)(dst + ob + jf * 512) = o;
            }
        }
    } else {
        // ---- Q/K: RoPE + pack to qkb (same formulas as old rope_kernel) ----
        int t = bn >> 10;                                 // 0=q, 1=k (uniform)
        int hh = ((bn + wn) >> 6) & 15;                   // wave-uniform head
        u16* base = qkb + (size_t)(t * 32 + b * 16 + hh) * (SEQ * HEAD_DIM);
        float scale = t ? 1.0f : 0.18033688011112043f;    // 0.125*log2(e) on q
        float f0 = expf(cc * -0.28782313662425572f);      // 10000^(-d1/32)
        float f1 = expf((16 + cc) * -0.28782313662425572f);
        const int o0 = ((cc >> 3) * 16) * 8 + (cc & 7);          // d1 = cc
        const int o1 = ((2 + (cc >> 3)) * 16) * 8 + (cc & 7);    // d1 = 16+cc
#pragma unroll
        for (int i = 0; i < 4; i++)
#pragma unroll
            for (int r = 0; r < 4; r++) {
                int pos = (m0 + i * 16 + quad * 4 + r) & 2047;
                int ob = (pos >> 4) * 1024 + (pos & 15) * 8;
                float s_, c_;
                __sincosf(pos * f0, &s_, &c_);
                float x1 = acc[i][0][r], x2 = acc[i][2][r];
                base[ob + o0]       = f2bf((x1 * c_ - x2 * s_) * scale);
                base[ob + o0 + 512] = f2bf((x2 * c_ + x1 * s_) * scale);
                __sincosf(pos * f1, &s_, &c_);
                x1 = acc[i][1][r]; x2 = acc[i][3][r];
                base[ob + o1]       = f2bf((x1 * c_ - x2 * s_) * scale);
                base[ob + o1 + 512] = f2bf((x2 * c_ + x1 * s_) * scale);
            }
    }
}

// GEMM2 split-K (2-phase dbuf): a2[4096][5120] @ W_out -> partials fp32
__global__ __launch_bounds__(256) void gemm2(const u16* __restrict__ a2,
        const u16* __restrict__ WoutT, float* __restrict__ p0, float* __restrict__ p1) {
    __shared__ u16 lds[2 * 8192];
    int bm = blockIdx.x * 128, bn = blockIdx.y * 128;
    int split = blockIdx.z;
    float* dst = split ? p1 : p0;
    f32x4 acc[4][4];
    gemm_core_128(a2 + split * 2560, VFF, WoutT + split * 2560, VFF, 2560,
                  bm, bn, acc, lds);
    const int tid = threadIdx.x, wid = tid >> 6, lane = tid & 63;
    const int quad = lane >> 4, cc = lane & 15;
    const int wm = (wid >> 1) * 64, wn = (wid & 1) * 64;
#pragma unroll
    for (int i = 0; i < 4; i++)
#pragma unroll
        for (int j = 0; j < 4; j++)
#pragma unroll
            for (int r = 0; r < 4; r++) {
                int m = bm + wm + i * 16 + quad * 4 + r;
                int n = bn + wn + j * 16 + cc;
                dst[(size_t)m * HIDDEN + n] = acc[i][j][r];
            }
}

__global__ __launch_bounds__(256) void reduce2(const float* __restrict__ p0,
        const float* __restrict__ p1, float* __restrict__ out) {
    int i = blockIdx.x * 256 + threadIdx.x;
    float4 a = ((const float4*)p0)[i];
    float4 b = ((const float4*)p1)[i];
    a.x += b.x; a.y += b.y; a.z += b.z; a.w += b.w;
    ((float4*)out)[i] = a;
}

// ------- Flash attention, causal, MFMA — FIXED-OFFSET softmax ---------------
// Q/K/V are pre-packed in MFMA fragment order (1KB blob per 16-row x 32-dim
// fragment, lane-major), so every fragment load is ONE contiguous 1KB wave
// load instead of a 16-segment row gather (R2 diagnosis: 256 divergent 64B
// transactions per chunk per wave -> MSHR/TA serialization, 73% stall).
// bh packing already gives each XCD a 4-head (2 MB) L2-resident K/V set.
__global__ __launch_bounds__(256) void attn_kernel(const u16* __restrict__ qk,
        const u16* __restrict__ vt, u16* __restrict__ a2) {
    const int id  = blockIdx.x;
    const int bh  = (id & 7) * 4 + ((id >> 3) & 3);
    const int bx  = id >> 5;
    const int tid = threadIdx.x;
    const int wid = tid >> 6;
    const int lane = tid & 63;
    const int quad = lane >> 4;
    const int cc = lane & 15;
    const int slot = wid >> 1;            // 0: tile bx, 1: tile 127-bx
    const int parity = wid & 1;
    const int tile = slot ? (127 - bx) : bx;
    const int q0 = tile * 16;

    const u16* Qp = qk + (size_t)bh * (SEQ * HEAD_DIM);
    const u16* Kp = qk + (size_t)(32 + bh) * (SEQ * HEAD_DIM);
    const u16* VP = vt + (size_t)bh * (HEAD_DIM * SEQ);

    __shared__ u16 Pbuf[4][16 * 72];      // per-wave P [q=16][key=64], stride 72
    __shared__ float obuf[2][64 * 17];    // merge: per-slot O^T (lane-major, pad 17)
    __shared__ float lbuf[2][16];         // merge: per-slot partial l per q
    u16* P = Pbuf[wid];

    const int bb = bh >> 4, hh = bh & 15;
    const int qcol = q0 + cc;

    // Q fragments from packed layout: one contiguous 1KB load per fragment
    bf16x8 qa0 = *(const bf16x8*)(Qp + (q0 >> 4) * 1024 + lane * 8);
    bf16x8 qa1 = *(const bf16x8*)(Qp + (q0 >> 4) * 1024 + 512 + lane * 8);

    float ps = 0.0f;                      // per-lane partial row-sum (this parity)
    f32x4 ot[4];                          // O^T: ot[mt][r] = O^T[d=mt*16+quad*4+r][q=cc]
#pragma unroll
    for (int mt = 0; mt < 4; mt++)
#pragma unroll
        for (int r = 0; r < 4; r++) ot[mt][r] = 0.0f;

    for (int kb = parity * 64; kb < q0 + 16; kb += 128) {
        const bool diag = (kb + 64 > q0);  // only the diagonal chunk needs masking
        // S^T = K Q^T - 32 (offset rides the accumulator init)
        f32x4 s[4];
        __builtin_amdgcn_s_setprio(1);
#pragma unroll
        for (int c = 0; c < 4; c++) {
            s[c][0] = -32.0f; s[c][1] = -32.0f; s[c][2] = -32.0f; s[c][3] = -32.0f;
            const u16* kblob = Kp + ((kb >> 4) + c) * 1024 + lane * 8;
            bf16x8 ka0 = *(const bf16x8*)(kblob);
            bf16x8 ka1 = *(const bf16x8*)(kblob + 512);
            s[c] = __builtin_amdgcn_mfma_f32_16x16x32_bf16(ka0, qa0, s[c], 0, 0, 0);
            s[c] = __builtin_amdgcn_mfma_f32_16x16x32_bf16(ka1, qa1, s[c], 0, 0, 0);
        }
        __builtin_amdgcn_s_setprio(0);
        // prefetch V^T for this chunk (overlaps the exp/stage phase)
        bf16x8 vf[2][4];
#pragma unroll
        for (int kc = 0; kc < 2; kc++)
#pragma unroll
            for (int mt = 0; mt < 4; mt++)
                vf[kc][mt] = *(const bf16x8*)(VP + ((kb >> 5) + kc) * 2048 + mt * 512 + lane * 8);
        // causal mask (diagonal chunk only; off-diag chunks are fully valid)
        if (diag) {
#pragma unroll
            for (int c = 0; c < 4; c++)
#pragma unroll
                for (int r = 0; r < 4; r++) {
                    int key = kb + c * 16 + quad * 4 + r;
                    s[c][r] = (key <= qcol) ? s[c][r] : -10000.0f;
                }
        }
        // P = exp2(s); local l accumulation (no cross-lane ops); cvt_pk pack
#pragma unroll
        for (int c = 0; c < 4; c++) {
            float p0v = exp2f(s[c][0]); ps += p0v;
            float p1v = exp2f(s[c][1]); ps += p1v;
            float p2v = exp2f(s[c][2]); ps += p2v;
            float p3v = exp2f(s[c][3]); ps += p3v;
            unsigned r0, r1;
            asm("v_cvt_pk_bf16_f32 %0, %1, %2" : "=v"(r0) : "v"(p0v), "v"(p1v));
            asm("v_cvt_pk_bf16_f32 %0, %1, %2" : "=v"(r1) : "v"(p2v), "v"(p3v));
            uint2 pk; pk.x = r0; pk.y = r1;
            *(uint2*)(P + cc * 72 + c * 16 + quad * 4) = pk;
        }
        asm volatile("s_waitcnt lgkmcnt(0)" ::: "memory");
        // O^T += V^T P^T
        __builtin_amdgcn_s_setprio(1);
#pragma unroll
        for (int kc = 0; kc < 2; kc++) {
            bf16x8 pb = *(const bf16x8*)(P + cc * 72 + kc * 32 + quad * 8);
#pragma unroll
            for (int mt = 0; mt < 4; mt++)
                ot[mt] = __builtin_amdgcn_mfma_f32_16x16x32_bf16(vf[kc][mt], pb, ot[mt], 0, 0, 0);
        }
        __builtin_amdgcn_s_setprio(0);
    }

    // ONE cross-lane l reduction (quads of same q-column)
    ps += __shfl_xor(ps, 16, 64);
    ps += __shfl_xor(ps, 32, 64);

    // ---- merge the two parity waves of each tile (plain add; no max) ----
    if (parity == 1) {
        if (quad == 0) lbuf[slot][cc] = ps;
        float* ob = obuf[slot] + lane * 17;
#pragma unroll
        for (int mt = 0; mt < 4; mt++)
#pragma unroll
            for (int r = 0; r < 4; r++) ob[mt * 4 + r] = ot[mt][r];
    }
    __syncthreads();
    if (parity == 0) {
        float l = ps + lbuf[slot][cc];
        float rl = 1.0f / l;
        const float* ob = obuf[slot] + lane * 17;
        u16* dst = a2 + ((size_t)(bb * SEQ + q0 + cc)) * VFF + hh * 64;
#pragma unroll
        for (int mt = 0; mt < 4; mt++) {
            ushort4 o;
            o.x = f2bf((ot[mt][0] + ob[mt * 4 + 0]) * rl);
            o.y = f2bf((ot[mt][1] + ob[mt * 4 + 1]) * rl);
            o.z = f2bf((ot[mt][2] + ob[mt * 4 + 2]) * rl);
            o.w = f2bf((ot[mt][3] + ob[mt * 4 + 3]) * rl);
            *(ushort4*)(dst + mt * 16 + quad * 4) = o;
        }
    }
}

extern "C" void kernel_launch(void* const* d_in, const int* in_sizes, int n_in,
                              void* d_out, int out_size, void* d_ws, size_t ws_size,
                              hipStream_t stream) {
    const float* x     = (const float*)d_in[0];
    const float* ln_w  = (const float*)d_in[1];
    const float* ln_b  = (const float*)d_in[2];
    const float* W_in  = (const float*)d_in[3];
    const float* W_out = (const float*)d_in[4];
    float* out = (float*)d_out;
    char* ws = (char*)d_ws;
    // Layout (peak 100663296 B):
    //   xn    @ 0         (8 MB)   dead after gemm1
    //   WinT  @ 8388608   (14 MB)  dead after gemm1
    //   qkb   @ 23068672  (16 MB)  gemm1 -> attn
    //   vtb   @ 39845888  (8 MB)   gemm1 -> attn
    //   WoutT @ 48234496  (10 MB)  -> gemm2
    //   a2    @ 58720256  (40 MB)  gemm1/attn -> gemm2
    //   p0    @ 0, p1 @ 16777216   gemm2 -> reduce2 (over dead xn/WinT/qkb)
    u16* xn    = (u16*)(ws);
    u16* WinT  = (u16*)(ws + 8388608);
    u16* qkb   = (u16*)(ws + 23068672);
    u16* vtb   = (u16*)(ws + 39845888);
    u16* WoutT = (u16*)(ws + 48234496);
    u16* a2    = (u16*)(ws + 58720256);
    float* p0  = (float*)(ws);
    float* p1  = (float*)(ws + 16777216);

    ln_kernel<<<dim3(MROWS), dim3(256), 0, stream>>>(x, ln_w, ln_b, xn);
    transpose_f2b<<<dim3(NQKVFF / 32, HIDDEN / 32), dim3(256), 0, stream>>>(W_in, WinT, HIDDEN, NQKVFF);
    transpose_f2b<<<dim3(HIDDEN / 32, VFF / 32), dim3(256), 0, stream>>>(W_out, WoutT, VFF, HIDDEN);
    gemm1<<<dim3(MROWS / 128, NQKVFF / 128), dim3(256), 0, stream>>>(xn, WinT, qkb, vtb, a2);
    attn_kernel<<<dim3(2048), dim3(256), 0, stream>>>(qkb, vtb, a2);
    gemm2<<<dim3(MROWS / 128, HIDDEN / 128, 2), dim3(256), 0, stream>>>(a2, WoutT, p0, p1);
    reduce2<<<dim3(MROWS * HIDDEN / 4 / 256), dim3(256), 0, stream>>>(p0, p1, out);
}

// Round 11
// 309.537 us; speedup vs baseline: 1.0879x; 1.0112x over previous
//
#include <hip/hip_runtime.h>
#include <math.h>

#define HEADS 16
#define HEAD_DIM 64
#define HIDDEN 1024
#define NQKVFF 7168
#define VFF 5120
#define SEQ 2048
#define MROWS 4096

typedef unsigned short u16;
typedef __attribute__((ext_vector_type(8))) short bf16x8;
typedef __attribute__((ext_vector_type(4))) float f32x4;
typedef __attribute__((address_space(1))) void gas_void;
typedef __attribute__((address_space(3))) void las_void;

__device__ inline u16 f2bf(float f) {
    union { float f; unsigned u; } v; v.f = f;
    unsigned r = v.u + 0x7FFFu + ((v.u >> 16) & 1u);
    return (u16)(r >> 16);
}
__device__ inline float bf2f(u16 h) {
    union { unsigned u; float f; } v; v.u = ((unsigned)h) << 16;
    return v.f;
}

// ---------------- LayerNorm: fp32 [4096][1024] -> bf16 [4096][1024] ----------
__global__ __launch_bounds__(256) void ln_kernel(const float* __restrict__ x,
        const float* __restrict__ w, const float* __restrict__ b,
        u16* __restrict__ xn) {
    int row = blockIdx.x;
    int tid = threadIdx.x;
    const float* xr = x + (size_t)row * HIDDEN;
    float4 v = ((const float4*)xr)[tid];
    float s = v.x + v.y + v.z + v.w;
    float sq = v.x * v.x + v.y * v.y + v.z * v.z + v.w * v.w;
    for (int off = 32; off > 0; off >>= 1) {
        s += __shfl_down(s, off, 64);
        sq += __shfl_down(sq, off, 64);
    }
    __shared__ float ls[4], lsq[4];
    int wid = tid >> 6, lane = tid & 63;
    if (lane == 0) { ls[wid] = s; lsq[wid] = sq; }
    __syncthreads();
    float ts = ls[0] + ls[1] + ls[2] + ls[3];
    float tsq = lsq[0] + lsq[1] + lsq[2] + lsq[3];
    float mu = ts * (1.0f / HIDDEN);
    float var = tsq * (1.0f / HIDDEN) - mu * mu;
    float rstd = rsqrtf(var + 1e-5f);
    float4 wv = ((const float4*)w)[tid];
    float4 bv = ((const float4*)b)[tid];
    ushort4 o;
    o.x = f2bf((v.x - mu) * rstd * wv.x + bv.x);
    o.y = f2bf((v.y - mu) * rstd * wv.y + bv.y);
    o.z = f2bf((v.z - mu) * rstd * wv.z + bv.z);
    o.w = f2bf((v.w - mu) * rstd * wv.w + bv.w);
    ((ushort4*)(xn + (size_t)row * HIDDEN))[tid] = o;
}

// ---------- Transpose + cast: fp32 in[R][C] -> bf16 out[C][R] ----------------
__global__ __launch_bounds__(256) void transpose_f2b(const float* __restrict__ in,
        u16* __restrict__ out, int R, int C) {
    __shared__ u16 tile[32][33];
    int c0 = blockIdx.x * 32, r0 = blockIdx.y * 32;
    int tx = threadIdx.x & 31, ty = threadIdx.x >> 5;
#pragma unroll
    for (int k = 0; k < 4; k++)
        tile[ty + k * 8][tx] = f2bf(in[(size_t)(r0 + ty + k * 8) * C + c0 + tx]);
    __syncthreads();
#pragma unroll
    for (int k = 0; k < 4; k++)
        out[(size_t)(c0 + ty + k * 8) * R + r0 + tx] = tile[tx][ty + k * 8];
}

// ---- 128x128 bf16 MFMA GEMM core, 3-BUFFER RING + COUNTED VMCNT (T3+T4) ----
// R7's 2-phase dbuf drains vmcnt(0) at every __syncthreads -> each staging
// load gets only ONE compute phase to cover its latency (the 27%-MfmaUtil
// ceiling, m233).  T4 fix (m218: counted-vmcnt IS the 8-phase gain): never
// drain in the loop.  3 LDS buffers (48 KB -> 3 blocks/CU); per K-step:
//   {s_waitcnt vmcnt(4); s_barrier}   <- single asm: no ds_read can slip
//                                        between wait and barrier
//   stage(t+2 -> buf[(t+2)%3])        <- loads span TWO compute phases
//   ds_read buf[t%3] + 16 MFMA
// Race-safety (each arrow barrier-separated): stage(t+2) overwrites the
// buffer read at t-1 -> all waves passed barrier(t) => done compute(t-1).
// A fast wave can't overwrite buf[t%3] until barrier(t+1) => all waves done
// compute(t).  vmcnt: 4 loads/thread/tile; outstanding at top of t = tiles
// t,t+1 -> wait vmcnt(4) keeps t+1 in flight (vmcnt(0) only at final tile).
// Raw-barrier + counted-vmcnt + global_load_lds is source-proven (m201).
__device__ inline void stage_tile(const u16* __restrict__ A, int lda,
                                  const u16* __restrict__ BT, int ldb,
                                  int bm, int bn, int k0, u16* dst,
                                  int row, int gch, int lofs) {
#pragma unroll
    for (int I = 0; I < 2; I++) {
        int r128 = I * 64 + row;
        const u16* ga = A + (size_t)(bm + r128) * lda + k0 + gch;
        __builtin_amdgcn_global_load_lds((gas_void*)ga,
                (las_void*)(dst + I * 2048 + lofs), 16, 0, 0);
        const u16* gb = BT + (size_t)(bn + r128) * ldb + k0 + gch;
        __builtin_amdgcn_global_load_lds((gas_void*)gb,
                (las_void*)(dst + 4096 + I * 2048 + lofs), 16, 0, 0);
    }
}

__device__ inline void gemm_core_128(const u16* __restrict__ A, int lda,
                                     const u16* __restrict__ BT, int ldb,
                                     int Klen, int bm, int bn, f32x4 acc[4][4],
                                     u16* lds) {
    const int tid = threadIdx.x;
    const int wid = tid >> 6;
    const int lane = tid & 63;
    const int quad = lane >> 4;
    const int cc = lane & 15;
    const int wm = (wid >> 1) * 64;
    const int wn = (wid & 1) * 64;
#pragma unroll
    for (int i = 0; i < 4; i++)
#pragma unroll
        for (int j = 0; j < 4; j++)
#pragma unroll
            for (int r = 0; r < 4; r++) acc[i][j][r] = 0.0f;

    const int row = tid >> 2;                       // 0..63
    const int gch = ((tid & 3) ^ ((row >> 1) & 3)) * 8;   // swizzled global chunk
    const int slot = (quad ^ ((cc >> 1) & 3)) * 8;        // swizzled read slot
    const int lofs = (tid & 192) * 8;               // wave's 512-u16 slice base

    const int nt = Klen >> 5;
    // prologue: stage tiles 0 and 1
    stage_tile(A, lda, BT, ldb, bm, bn, 0,  lds,        row, gch, lofs);
    stage_tile(A, lda, BT, ldb, bm, bn, 32, lds + 8192, row, gch, lofs);

    for (int t = 0; t < nt; ++t) {
        if (t + 1 < nt)
            asm volatile("s_waitcnt vmcnt(4)\n\ts_barrier" ::: "memory");
        else
            asm volatile("s_waitcnt vmcnt(0)\n\ts_barrier" ::: "memory");
        u16* cur = lds + (unsigned)(t % 3) * 8192;
        if (t + 2 < nt)
            stage_tile(A, lda, BT, ldb, bm, bn, (t + 2) * 32,
                       lds + (unsigned)((t + 2) % 3) * 8192, row, gch, lofs);
        bf16x8 af[4], bfr[4];
#pragma unroll
        for (int u = 0; u < 4; u++) {
            af[u]  = *(const bf16x8*)(cur + (wm + u * 16 + cc) * 32 + slot);
            bfr[u] = *(const bf16x8*)(cur + 4096 + (wn + u * 16 + cc) * 32 + slot);
        }
        __builtin_amdgcn_s_setprio(1);
#pragma unroll
        for (int i = 0; i < 4; i++)
#pragma unroll
            for (int j = 0; j < 4; j++)
                acc[i][j] = __builtin_amdgcn_mfma_f32_16x16x32_bf16(af[i], bfr[j], acc[i][j], 0, 0, 0);
        __builtin_amdgcn_s_setprio(0);
    }
}

// exp2-based tanh GELU (max |err| vs exact ~3e-3, well under threshold)
__device__ inline float gelu_f(float v) {
    float u = v * (v * v * 0.044715f + 1.0f) * 0.7978845608028654f;
    u = fminf(u, 15.0f);                       // saturate (avoid inf/inf)
    float e = exp2f(u * 2.8853900817779268f);  // e^(2u)
    return v * (e / (e + 1.0f));               // v * 0.5*(1+tanh(u))
}

// GEMM1 FUSED (128x128, 3-buf counted-vmcnt): xn @ W_in, epilogue by bn:
//   bn <  2048: RoPE + scatter into MFMA-fragment-packed qkb
//   bn <  3072: pack into MFMA-fragment-packed vtb
//   bn >= 3072: gelu -> a2[:, 1024:]
// (R4-verified epilogues, R3-verified packed layouts.)
__global__ __launch_bounds__(256) void gemm1(const u16* __restrict__ xn,
        const u16* __restrict__ WinT, u16* __restrict__ qkb,
        u16* __restrict__ vtb, u16* __restrict__ a2) {
    __shared__ u16 lds[3 * 8192];
    int bm = blockIdx.x * 128, bn = blockIdx.y * 128;
    f32x4 acc[4][4];
    gemm_core_128(xn, HIDDEN, WinT, HIDDEN, HIDDEN, bm, bn, acc, lds);
    const int tid = threadIdx.x, wid = tid >> 6, lane = tid & 63;
    const int quad = lane >> 4, cc = lane & 15;
    const int wm = (wid >> 1) * 64, wn = (wid & 1) * 64;
    const int m0 = bm + wm;             // wave's first output row (64-aligned)
    const int b = m0 >> 11;             // batch index (wave-uniform)

    if (bn >= 3072) {
        // ---- FF: gelu -> a2 cols 1024..5119 ----
#pragma unroll
        for (int i = 0; i < 4; i++)
#pragma unroll
            for (int j = 0; j < 4; j++)
#pragma unroll
                for (int r = 0; r < 4; r++) {
                    int m = m0 + i * 16 + quad * 4 + r;
                    int n = bn + wn + j * 16 + cc;
                    a2[(size_t)m * VFF + (n - 2048)] = f2bf(gelu_f(acc[i][j][r]));
                }
    } else if (bn >= 2048) {
        // ---- V: pack to vtb[bh][key>>5][d>>4][((key&31)>>3)*16 + (d&15)][key&7]
        int hh = ((bn - 2048 + wn) >> 6) & 15;           // wave-uniform head
        u16* dst = vtb + (size_t)(b * 16 + hh) * (HEAD_DIM * SEQ);
#pragma unroll
        for (int i = 0; i < 4; i++) {
            int key0 = (m0 + i * 16 + quad * 4) & 2047;  // r=0..3 consecutive
            size_t ob = (size_t)(key0 >> 5) * 2048 +
                        (((key0 & 31) >> 3) * 16 + cc) * 8 + (key0 & 7);
#pragma unroll
            for (int jf = 0; jf < 4; jf++) {             // d = jf*16 + cc
                ushort4 o;
                o.x = f2bf(acc[i][jf][0]);
                o.y = f2bf(acc[i][jf][1]);
                o.z = f2bf(acc[i][jf][2]);
                o.w = f2bf(acc[i][jf][3]);
                *(ushort4*)(dst + ob + jf * 512) = o;
            }
        }
    } else {
        // ---- Q/K: RoPE + pack to qkb (same formulas as old rope_kernel) ----
        int t = bn >> 10;                                 // 0=q, 1=k (uniform)
        int hh = ((bn + wn) >> 6) & 15;                   // wave-uniform head
        u16* base = qkb + (size_t)(t * 32 + b * 16 + hh) * (SEQ * HEAD_DIM);
        float scale = t ? 1.0f : 0.18033688011112043f;    // 0.125*log2(e) on q
        float f0 = expf(cc * -0.28782313662425572f);      // 10000^(-d1/32)
        float f1 = expf((16 + cc) * -0.28782313662425572f);
        const int o0 = ((cc >> 3) * 16) * 8 + (cc & 7);          // d1 = cc
        const int o1 = ((2 + (cc >> 3)) * 16) * 8 + (cc & 7);    // d1 = 16+cc
#pragma unroll
        for (int i = 0; i < 4; i++)
#pragma unroll
            for (int r = 0; r < 4; r++) {
                int pos = (m0 + i * 16 + quad * 4 + r) & 2047;
                int ob = (pos >> 4) * 1024 + (pos & 15) * 8;
                float s_, c_;
                __sincosf(pos * f0, &s_, &c_);
                float x1 = acc[i][0][r], x2 = acc[i][2][r];
                base[ob + o0]       = f2bf((x1 * c_ - x2 * s_) * scale);
                base[ob + o0 + 512] = f2bf((x2 * c_ + x1 * s_) * scale);
                __sincosf(pos * f1, &s_, &c_);
                x1 = acc[i][1][r]; x2 = acc[i][3][r];
                base[ob + o1]       = f2bf((x1 * c_ - x2 * s_) * scale);
                base[ob + o1 + 512] = f2bf((x2 * c_ + x1 * s_) * scale);
            }
    }
}

// GEMM2 split-K (3-buf counted-vmcnt): a2[4096][5120] @ W_out -> fp32 partials
__global__ __launch_bounds__(256) void gemm2(const u16* __restrict__ a2,
        const u16* __restrict__ WoutT, float* __restrict__ p0, float* __restrict__ p1) {
    __shared__ u16 lds[3 * 8192];
    int bm = blockIdx.x * 128, bn = blockIdx.y * 128;
    int split = blockIdx.z;
    float* dst = split ? p1 : p0;
    f32x4 acc[4][4];
    gemm_core_128(a2 + split * 2560, VFF, WoutT + split * 2560, VFF, 2560,
                  bm, bn, acc, lds);
    const int tid = threadIdx.x, wid = tid >> 6, lane = tid & 63;
    const int quad = lane >> 4, cc = lane & 15;
    const int wm = (wid >> 1) * 64, wn = (wid & 1) * 64;
#pragma unroll
    for (int i = 0; i < 4; i++)
#pragma unroll
        for (int j = 0; j < 4; j++)
#pragma unroll
            for (int r = 0; r < 4; r++) {
                int m = bm + wm + i * 16 + quad * 4 + r;
                int n = bn + wn + j * 16 + cc;
                dst[(size_t)m * HIDDEN + n] = acc[i][j][r];
            }
}

__global__ __launch_bounds__(256) void reduce2(const float* __restrict__ p0,
        const float* __restrict__ p1, float* __restrict__ out) {
    int i = blockIdx.x * 256 + threadIdx.x;
    float4 a = ((const float4*)p0)[i];
    float4 b = ((const float4*)p1)[i];
    a.x += b.x; a.y += b.y; a.z += b.z; a.w += b.w;
    ((float4*)out)[i] = a;
}

// ------- Flash attention, causal, MFMA — FIXED-OFFSET softmax ---------------
// Q/K/V are pre-packed in MFMA fragment order (1KB blob per 16-row x 32-dim
// fragment, lane-major), so every fragment load is ONE contiguous 1KB wave
// load instead of a 16-segment row gather (R2 diagnosis: 256 divergent 64B
// transactions per chunk per wave -> MSHR/TA serialization, 73% stall).
// bh packing already gives each XCD a 4-head (2 MB) L2-resident K/V set.
__global__ __launch_bounds__(256) void attn_kernel(const u16* __restrict__ qk,
        const u16* __restrict__ vt, u16* __restrict__ a2) {
    const int id  = blockIdx.x;
    const int bh  = (id & 7) * 4 + ((id >> 3) & 3);
    const int bx  = id >> 5;
    const int tid = threadIdx.x;
    const int wid = tid >> 6;
    const int lane = tid & 63;
    const int quad = lane >> 4;
    const int cc = lane & 15;
    const int slot = wid >> 1;            // 0: tile bx, 1: tile 127-bx
    const int parity = wid & 1;
    const int tile = slot ? (127 - bx) : bx;
    const int q0 = tile * 16;

    const u16* Qp = qk + (size_t)bh * (SEQ * HEAD_DIM);
    const u16* Kp = qk + (size_t)(32 + bh) * (SEQ * HEAD_DIM);
    const u16* VP = vt + (size_t)bh * (HEAD_DIM * SEQ);

    __shared__ u16 Pbuf[4][16 * 72];      // per-wave P [q=16][key=64], stride 72
    __shared__ float obuf[2][64 * 17];    // merge: per-slot O^T (lane-major, pad 17)
    __shared__ float lbuf[2][16];         // merge: per-slot partial l per q
    u16* P = Pbuf[wid];

    const int bb = bh >> 4, hh = bh & 15;
    const int qcol = q0 + cc;

    // Q fragments from packed layout: one contiguous 1KB load per fragment
    bf16x8 qa0 = *(const bf16x8*)(Qp + (q0 >> 4) * 1024 + lane * 8);
    bf16x8 qa1 = *(const bf16x8*)(Qp + (q0 >> 4) * 1024 + 512 + lane * 8);

    float ps = 0.0f;                      // per-lane partial row-sum (this parity)
    f32x4 ot[4];                          // O^T: ot[mt][r] = O^T[d=mt*16+quad*4+r][q=cc]
#pragma unroll
    for (int mt = 0; mt < 4; mt++)
#pragma unroll
        for (int r = 0; r < 4; r++) ot[mt][r] = 0.0f;

    for (int kb = parity * 64; kb < q0 + 16; kb += 128) {
        const bool diag = (kb + 64 > q0);  // only the diagonal chunk needs masking
        // S^T = K Q^T - 32 (offset rides the accumulator init)
        f32x4 s[4];
        __builtin_amdgcn_s_setprio(1);
#pragma unroll
        for (int c = 0; c < 4; c++) {
            s[c][0] = -32.0f; s[c][1] = -32.0f; s[c][2] = -32.0f; s[c][3] = -32.0f;
            const u16* kblob = Kp + ((kb >> 4) + c) * 1024 + lane * 8;
            bf16x8 ka0 = *(const bf16x8*)(kblob);
            bf16x8 ka1 = *(const bf16x8*)(kblob + 512);
            s[c] = __builtin_amdgcn_mfma_f32_16x16x32_bf16(ka0, qa0, s[c], 0, 0, 0);
            s[c] = __builtin_amdgcn_mfma_f32_16x16x32_bf16(ka1, qa1, s[c], 0, 0, 0);
        }
        __builtin_amdgcn_s_setprio(0);
        // prefetch V^T for this chunk (overlaps the exp/stage phase)
        bf16x8 vf[2][4];
#pragma unroll
        for (int kc = 0; kc < 2; kc++)
#pragma unroll
            for (int mt = 0; mt < 4; mt++)
                vf[kc][mt] = *(const bf16x8*)(VP + ((kb >> 5) + kc) * 2048 + mt * 512 + lane * 8);
        // causal mask (diagonal chunk only; off-diag chunks are fully valid)
        if (diag) {
#pragma unroll
            for (int c = 0; c < 4; c++)
#pragma unroll
                for (int r = 0; r < 4; r++) {
                    int key = kb + c * 16 + quad * 4 + r;
                    s[c][r] = (key <= qcol) ? s[c][r] : -10000.0f;
                }
        }
        // P = exp2(s); local l accumulation (no cross-lane ops); cvt_pk pack
#pragma unroll
        for (int c = 0; c < 4; c++) {
            float p0v = exp2f(s[c][0]); ps += p0v;
            float p1v = exp2f(s[c][1]); ps += p1v;
            float p2v = exp2f(s[c][2]); ps += p2v;
            float p3v = exp2f(s[c][3]); ps += p3v;
            unsigned r0, r1;
            asm("v_cvt_pk_bf16_f32 %0, %1, %2" : "=v"(r0) : "v"(p0v), "v"(p1v));
            asm("v_cvt_pk_bf16_f32 %0, %1, %2" : "=v"(r1) : "v"(p2v), "v"(p3v));
            uint2 pk; pk.x = r0; pk.y = r1;
            *(uint2*)(P + cc * 72 + c * 16 + quad * 4) = pk;
        }
        asm volatile("s_waitcnt lgkmcnt(0)" ::: "memory");
        // O^T += V^T P^T
        __builtin_amdgcn_s_setprio(1);
#pragma unroll
        for (int kc = 0; kc < 2; kc++) {
            bf16x8 pb = *(const bf16x8*)(P + cc * 72 + kc * 32 + quad * 8);
#pragma unroll
            for (int mt = 0; mt < 4; mt++)
                ot[mt] = __builtin_amdgcn_mfma_f32_16x16x32_bf16(vf[kc][mt], pb, ot[mt], 0, 0, 0);
        }
        __builtin_amdgcn_s_setprio(0);
    }

    // ONE cross-lane l reduction (quads of same q-column)
    ps += __shfl_xor(ps, 16, 64);
    ps += __shfl_xor(ps, 32, 64);

    // ---- merge the two parity waves of each tile (plain add; no max) ----
    if (parity == 1) {
        if (quad == 0) lbuf[slot][cc] = ps;
        float* ob = obuf[slot] + lane * 17;
#pragma unroll
        for (int mt = 0; mt < 4; mt++)
#pragma unroll
            for (int r = 0; r < 4; r++) ob[mt * 4 + r] = ot[mt][r];
    }
    __syncthreads();
    if (parity == 0) {
        float l = ps + lbuf[slot][cc];
        float rl = 1.0f / l;
        const float* ob = obuf[slot] + lane * 17;
        u16* dst = a2 + ((size_t)(bb * SEQ + q0 + cc)) * VFF + hh * 64;
#pragma unroll
        for (int mt = 0; mt < 4; mt++) {
            ushort4 o;
            o.x = f2bf((ot[mt][0] + ob[mt * 4 + 0]) * rl);
            o.y = f2bf((ot[mt][1] + ob[mt * 4 + 1]) * rl);
            o.z = f2bf((ot[mt][2] + ob[mt * 4 + 2]) * rl);
            o.w = f2bf((ot[mt][3] + ob[mt * 4 + 3]) * rl);
            *(ushort4*)(dst + mt * 16 + quad * 4) = o;
        }
    }
}

extern "C" void kernel_launch(void* const* d_in, const int* in_sizes, int n_in,
                              void* d_out, int out_size, void* d_ws, size_t ws_size,
                              hipStream_t stream) {
    const float* x     = (const float*)d_in[0];
    const float* ln_w  = (const float*)d_in[1];
    const float* ln_b  = (const float*)d_in[2];
    const float* W_in  = (const float*)d_in[3];
    const float* W_out = (const float*)d_in[4];
    float* out = (float*)d_out;
    char* ws = (char*)d_ws;
    // Layout (peak 100663296 B):
    //   xn    @ 0         (8 MB)   dead after gemm1
    //   WinT  @ 8388608   (14 MB)  dead after gemm1
    //   qkb   @ 23068672  (16 MB)  gemm1 -> attn
    //   vtb   @ 39845888  (8 MB)   gemm1 -> attn
    //   WoutT @ 48234496  (10 MB)  -> gemm2
    //   a2    @ 58720256  (40 MB)  gemm1/attn -> gemm2
    //   p0    @ 0, p1 @ 16777216   gemm2 -> reduce2 (over dead xn/WinT/qkb)
    u16* xn    = (u16*)(ws);
    u16* WinT  = (u16*)(ws + 8388608);
    u16* qkb   = (u16*)(ws + 23068672);
    u16* vtb   = (u16*)(ws + 39845888);
    u16* WoutT = (u16*)(ws + 48234496);
    u16* a2    = (u16*)(ws + 58720256);
    float* p0  = (float*)(ws);
    float* p1  = (float*)(ws + 16777216);

    ln_kernel<<<dim3(MROWS), dim3(256), 0, stream>>>(x, ln_w, ln_b, xn);
    transpose_f2b<<<dim3(NQKVFF / 32, HIDDEN / 32), dim3(256), 0, stream>>>(W_in, WinT, HIDDEN, NQKVFF);
    transpose_f2b<<<dim3(HIDDEN / 32, VFF / 32), dim3(256), 0, stream>>>(W_out, WoutT, VFF, HIDDEN);
    gemm1<<<dim3(MROWS / 128, NQKVFF / 128), dim3(256), 0, stream>>>(xn, WinT, qkb, vtb, a2);
    attn_kernel<<<dim3(2048), dim3(256), 0, stream>>>(qkb, vtb, a2);
    gemm2<<<dim3(MROWS / 128, HIDDEN / 128, 2), dim3(256), 0, stream>>>(a2, WoutT, p0, p1);
    reduce2<<<dim3(MROWS * HIDDEN / 4 / 256), dim3(256), 0, stream>>>(p0, p1, out);
}

// Round 12
// 290.075 us; speedup vs baseline: 1.1609x; 1.0671x over previous
//
#include <hip/hip_runtime.h>
#include <math.h>

#define HEADS 16
#define HEAD_DIM 64
#define HIDDEN 1024
#define NQKVFF 7168
#define VFF 5120
#define SEQ 2048
#define MROWS 4096
#define G1NT 16   // gemm1 K-tiles: 1024 / 64

typedef unsigned short u16;
typedef __attribute__((ext_vector_type(8))) short bf16x8;
typedef __attribute__((ext_vector_type(4))) float f32x4;
typedef __attribute__((address_space(1))) void gas_void;
typedef __attribute__((address_space(3))) void las_void;

__device__ inline u16 f2bf(float f) {
    union { float f; unsigned u; } v; v.f = f;
    unsigned r = v.u + 0x7FFFu + ((v.u >> 16) & 1u);
    return (u16)(r >> 16);
}
__device__ inline float bf2f(u16 h) {
    union { unsigned u; float f; } v; v.u = ((unsigned)h) << 16;
    return v.f;
}

// ---------------- LayerNorm: fp32 [4096][1024] -> bf16 [4096][1024] ----------
__global__ __launch_bounds__(256) void ln_kernel(const float* __restrict__ x,
        const float* __restrict__ w, const float* __restrict__ b,
        u16* __restrict__ xn) {
    int row = blockIdx.x;
    int tid = threadIdx.x;
    const float* xr = x + (size_t)row * HIDDEN;
    float4 v = ((const float4*)xr)[tid];
    float s = v.x + v.y + v.z + v.w;
    float sq = v.x * v.x + v.y * v.y + v.z * v.z + v.w * v.w;
    for (int off = 32; off > 0; off >>= 1) {
        s += __shfl_down(s, off, 64);
        sq += __shfl_down(sq, off, 64);
    }
    __shared__ float ls[4], lsq[4];
    int wid = tid >> 6, lane = tid & 63;
    if (lane == 0) { ls[wid] = s; lsq[wid] = sq; }
    __syncthreads();
    float ts = ls[0] + ls[1] + ls[2] + ls[3];
    float tsq = lsq[0] + lsq[1] + lsq[2] + lsq[3];
    float mu = ts * (1.0f / HIDDEN);
    float var = tsq * (1.0f / HIDDEN) - mu * mu;
    float rstd = rsqrtf(var + 1e-5f);
    float4 wv = ((const float4*)w)[tid];
    float4 bv = ((const float4*)b)[tid];
    ushort4 o;
    o.x = f2bf((v.x - mu) * rstd * wv.x + bv.x);
    o.y = f2bf((v.y - mu) * rstd * wv.y + bv.y);
    o.z = f2bf((v.z - mu) * rstd * wv.z + bv.z);
    o.w = f2bf((v.w - mu) * rstd * wv.w + bv.w);
    ((ushort4*)(xn + (size_t)row * HIDDEN))[tid] = o;
}

// ---------- Transpose + cast: fp32 in[R][C] -> bf16 out[C][R] ----------------
__global__ __launch_bounds__(256) void transpose_f2b(const float* __restrict__ in,
        u16* __restrict__ out, int R, int C) {
    __shared__ u16 tile[32][33];
    int c0 = blockIdx.x * 32, r0 = blockIdx.y * 32;
    int tx = threadIdx.x & 31, ty = threadIdx.x >> 5;
#pragma unroll
    for (int k = 0; k < 4; k++)
        tile[ty + k * 8][tx] = f2bf(in[(size_t)(r0 + ty + k * 8) * C + c0 + tx]);
    __syncthreads();
#pragma unroll
    for (int k = 0; k < 4; k++)
        out[(size_t)(c0 + ty + k * 8) * R + r0 + tx] = tile[tx][ty + k * 8];
}

// ------- 128x128 bf16 MFMA GEMM core, DOUBLE-BUFFERED 2-phase (T3-min) -------
// (R7-verified; used by gemm2.  R11 lesson: counted-vmcnt 3-buf ring was NULL
// on this structure — T4 pays only inside the 8-phase interleave.)
__device__ inline void gemm_core_128(const u16* __restrict__ A, int lda,
                                     const u16* __restrict__ BT, int ldb,
                                     int Klen, int bm, int bn, f32x4 acc[4][4],
                                     u16* lds) {
    const int tid = threadIdx.x;
    const int wid = tid >> 6;
    const int lane = tid & 63;
    const int quad = lane >> 4;
    const int cc = lane & 15;
    const int wm = (wid >> 1) * 64;
    const int wn = (wid & 1) * 64;
#pragma unroll
    for (int i = 0; i < 4; i++)
#pragma unroll
        for (int j = 0; j < 4; j++)
#pragma unroll
            for (int r = 0; r < 4; r++) acc[i][j][r] = 0.0f;

    const int row = tid >> 2;                       // 0..63
    const int gch = ((tid & 3) ^ ((row >> 1) & 3)) * 8;   // swizzled global chunk
    const int slot = (quad ^ ((cc >> 1) & 3)) * 8;        // swizzled read slot
    const int lofs = (tid & 192) * 8;               // wave's 512-u16 slice base

    u16* cur = lds;
    u16* nxt = lds + 8192;

    // prologue: stage tile 0
#pragma unroll
    for (int I = 0; I < 2; I++) {
        int r128 = I * 64 + row;
        const u16* ga = A + (size_t)(bm + r128) * lda + gch;
        __builtin_amdgcn_global_load_lds((gas_void*)ga,
                (las_void*)(cur + I * 2048 + lofs), 16, 0, 0);
        const u16* gb = BT + (size_t)(bn + r128) * ldb + gch;
        __builtin_amdgcn_global_load_lds((gas_void*)gb,
                (las_void*)(cur + 4096 + I * 2048 + lofs), 16, 0, 0);
    }
    __syncthreads();

    for (int k0 = 0; k0 < Klen; k0 += 32) {
        const bool more = (k0 + 32 < Klen);
        if (more) {
            // issue next tile's staging loads FIRST (overlap with compute)
#pragma unroll
            for (int I = 0; I < 2; I++) {
                int r128 = I * 64 + row;
                const u16* ga = A + (size_t)(bm + r128) * lda + k0 + 32 + gch;
                __builtin_amdgcn_global_load_lds((gas_void*)ga,
                        (las_void*)(nxt + I * 2048 + lofs), 16, 0, 0);
                const u16* gb = BT + (size_t)(bn + r128) * ldb + k0 + 32 + gch;
                __builtin_amdgcn_global_load_lds((gas_void*)gb,
                        (las_void*)(nxt + 4096 + I * 2048 + lofs), 16, 0, 0);
            }
        }
        bf16x8 af[4], bfr[4];
#pragma unroll
        for (int t = 0; t < 4; t++) {
            af[t]  = *(const bf16x8*)(cur + (wm + t * 16 + cc) * 32 + slot);
            bfr[t] = *(const bf16x8*)(cur + 4096 + (wn + t * 16 + cc) * 32 + slot);
        }
        __builtin_amdgcn_s_setprio(1);
#pragma unroll
        for (int i = 0; i < 4; i++)
#pragma unroll
            for (int j = 0; j < 4; j++)
                acc[i][j] = __builtin_amdgcn_mfma_f32_16x16x32_bf16(af[i], bfr[j], acc[i][j], 0, 0, 0);
        __builtin_amdgcn_s_setprio(0);
        if (more) __syncthreads();   // drains vmcnt(0): next tile fully in LDS
        u16* tmp = cur; cur = nxt; nxt = tmp;
    }
}

// ---- 256x256 staging helper: one 128-row x 64-col half-tile, 3-bit XOR ------
// Row = 128 B = 8 16B chunks.  Physical slot s holds global chunk s^((r>>1)&7)
// (global-source permutation; global_load_lds lane->LDS mapping is linear).
// Reads at slot (ch ^ sw) then land 8 lanes per 16B slot-column = bank-optimal.
__device__ __forceinline__ void stage_half_256(const u16* __restrict__ src,
        int ld, int row0, int k0, u16* dsthalf, int tid) {
#pragma unroll
    for (int I = 0; I < 2; I++) {
        int r = (tid >> 3) + I * 64;                 // row in half (0..127)
        int g = (tid & 7) ^ ((r >> 1) & 7);          // global chunk for my slot
        const u16* ga = src + (size_t)(row0 + r) * ld + k0 + g * 8;
        __builtin_amdgcn_global_load_lds((gas_void*)ga,
                (las_void*)(dsthalf + I * 4096 + (tid & 0x1C0) * 8), 16, 0, 0);
    }
}

// exp2-based tanh GELU (max |err| vs exact ~3e-3, well under threshold)
__device__ inline float gelu_f(float v) {
    float u = v * (v * v * 0.044715f + 1.0f) * 0.7978845608028654f;
    u = fminf(u, 15.0f);                       // saturate (avoid inf/inf)
    float e = exp2f(u * 2.8853900817779268f);  // e^(2u)
    return v * (e / (e + 1.0f));               // v * 0.5*(1+tanh(u))
}

// GEMM1 FUSED — 256x256 tile, 8 waves (2M x 4N), BK=64, double-buffered.
// R11 lesson: 128^2 pipeline-depth tricks are null; geometry is the lever
// (m230: 256^2 +10%; K=64 halves barrier-drains/MFMA and doubles
// MFMA-per-staged-byte).  Schedule per K-tile (provably race-free):
//   {s_waitcnt vmcnt(0); s_barrier}        <- drain tile t's stages (once/K64)
//   stage all 4 half-tiles of t+1 -> buf^1 <- full-tile flight before drain
//   4 quadrant phases: ds_read + 16 MFMA   <- reads buf (drained), no hazards
// Stage writes touch buf^1 only; its last readers finished before this tile's
// barrier.  Per-element K order (32-chunks ascending) identical to R7.
// Epilogue by wave column nb (64-wide = one head; all region boundaries are
// multiples of 256 so blocks never straddle).
__global__ __launch_bounds__(512, 2) void gemm1(const u16* __restrict__ xn,
        const u16* __restrict__ WinT, u16* __restrict__ qkb,
        u16* __restrict__ vtb, u16* __restrict__ a2) {
    __shared__ u16 lds[2 * 32768];      // [buf][A 16K u16 | B 16K u16]
    const int tid = threadIdx.x;
    const int wid = tid >> 6;
    const int lane = tid & 63;
    const int quad = lane >> 4;
    const int cc = lane & 15;
    const int wr = wid >> 2;            // 0..1 (M)
    const int wc = wid & 3;             // 0..3 (N)
    const int bm = blockIdx.x * 256, bn = blockIdx.y * 256;
    const int wrbase = wr * 128;
    const int wcbase = wc * 64;

    f32x4 acc[8][4];
#pragma unroll
    for (int i = 0; i < 8; i++)
#pragma unroll
        for (int j = 0; j < 4; j++)
#pragma unroll
            for (int r = 0; r < 4; r++) acc[i][j][r] = 0.0f;

    // prologue: stage tile 0 into buf 0
    stage_half_256(xn,   HIDDEN, bm,       0, lds,                 tid);
    stage_half_256(xn,   HIDDEN, bm + 128, 0, lds + 8192,          tid);
    stage_half_256(WinT, HIDDEN, bn,       0, lds + 16384,         tid);
    stage_half_256(WinT, HIDDEN, bn + 128, 0, lds + 16384 + 8192,  tid);

#pragma unroll 1
    for (int t = 0; t < G1NT; ++t) {
        asm volatile("s_waitcnt vmcnt(0)\n\ts_barrier" ::: "memory");
        const u16* buf = lds + (t & 1) * 32768;
        if (t + 1 < G1NT) {
            u16* nbuf = lds + ((t + 1) & 1) * 32768;
            int k1 = (t + 1) * 64;
            stage_half_256(xn,   HIDDEN, bm,       k1, nbuf,                tid);
            stage_half_256(xn,   HIDDEN, bm + 128, k1, nbuf + 8192,         tid);
            stage_half_256(WinT, HIDDEN, bn,       k1, nbuf + 16384,        tid);
            stage_half_256(WinT, HIDDEN, bn + 128, k1, nbuf + 16384 + 8192, tid);
        }
#pragma unroll
        for (int mh = 0; mh < 2; mh++) {
            bf16x8 af[4][2];
#pragma unroll
            for (int i2 = 0; i2 < 4; i2++) {
                int r = wrbase + (mh * 4 + i2) * 16 + cc;
                const u16* pa = buf + ((r >> 7) << 13) + ((r & 127) << 6);
                int sw = (r >> 1) & 7;
                af[i2][0] = *(const bf16x8*)(pa + ((quad ^ sw) << 3));
                af[i2][1] = *(const bf16x8*)(pa + (((4 + quad) ^ sw) << 3));
            }
#pragma unroll
            for (int nh = 0; nh < 2; nh++) {
                bf16x8 bfr[2][2];
#pragma unroll
                for (int j2 = 0; j2 < 2; j2++) {
                    int r = wcbase + (nh * 2 + j2) * 16 + cc;
                    const u16* pb = buf + 16384 + ((r >> 7) << 13) + ((r & 127) << 6);
                    int sw = (r >> 1) & 7;
                    bfr[j2][0] = *(const bf16x8*)(pb + ((quad ^ sw) << 3));
                    bfr[j2][1] = *(const bf16x8*)(pb + (((4 + quad) ^ sw) << 3));
                }
                __builtin_amdgcn_s_setprio(1);
#pragma unroll
                for (int i2 = 0; i2 < 4; i2++)
#pragma unroll
                    for (int j2 = 0; j2 < 2; j2++) {
                        int ii = mh * 4 + i2, jj = nh * 2 + j2;
                        acc[ii][jj] = __builtin_amdgcn_mfma_f32_16x16x32_bf16(af[i2][0], bfr[j2][0], acc[ii][jj], 0, 0, 0);
                        acc[ii][jj] = __builtin_amdgcn_mfma_f32_16x16x32_bf16(af[i2][1], bfr[j2][1], acc[ii][jj], 0, 0, 0);
                    }
                __builtin_amdgcn_s_setprio(0);
            }
        }
    }

    // ---- epilogue (R4-verified formulas; i extended to 8 m-fragments) ----
    const int m0 = bm + wrbase;         // wave's first output row (128-aligned)
    const int b = m0 >> 11;             // batch index (wave-uniform)
    const int nb = bn + wcbase;         // wave's first output col (64-aligned)

    if (nb >= 3072) {
        // ---- FF: gelu -> a2 cols 1024..5119 ----
#pragma unroll
        for (int i = 0; i < 8; i++)
#pragma unroll
            for (int j = 0; j < 4; j++)
#pragma unroll
                for (int r = 0; r < 4; r++) {
                    int m = m0 + i * 16 + quad * 4 + r;
                    int n = nb + j * 16 + cc;
                    a2[(size_t)m * VFF + (n - 2048)] = f2bf(gelu_f(acc[i][j][r]));
                }
    } else if (nb >= 2048) {
        // ---- V: pack to vtb[bh][key>>5][d>>4][((key&31)>>3)*16 + (d&15)][key&7]
        int hh = ((nb - 2048) >> 6) & 15;                // wave-uniform head
        u16* dst = vtb + (size_t)(b * 16 + hh) * (HEAD_DIM * SEQ);
#pragma unroll
        for (int i = 0; i < 8; i++) {
            int key0 = (m0 + i * 16 + quad * 4) & 2047;  // r=0..3 consecutive
            size_t ob = (size_t)(key0 >> 5) * 2048 +
                        (((key0 & 31) >> 3) * 16 + cc) * 8 + (key0 & 7);
#pragma unroll
            for (int jf = 0; jf < 4; jf++) {             // d = jf*16 + cc
                ushort4 o;
                o.x = f2bf(acc[i][jf][0]);
                o.y = f2bf(acc[i][jf][1]);
                o.z = f2bf(acc[i][jf][2]);
                o.w = f2bf(acc[i][jf][3]);
                *(ushort4*)(dst + ob + jf * 512) = o;
            }
        }
    } else {
        // ---- Q/K: RoPE + pack to qkb (formulas identical to R4) ----
        int tq = nb >> 10;                               // 0=q, 1=k (uniform)
        int hh = (nb >> 6) & 15;                         // wave-uniform head
        u16* base = qkb + (size_t)(tq * 32 + b * 16 + hh) * (SEQ * HEAD_DIM);
        float scale = tq ? 1.0f : 0.18033688011112043f;  // 0.125*log2(e) on q
        float f0 = expf(cc * -0.28782313662425572f);     // 10000^(-d1/32)
        float f1 = expf((16 + cc) * -0.28782313662425572f);
        const int o0 = ((cc >> 3) * 16) * 8 + (cc & 7);        // d1 = cc
        const int o1 = ((2 + (cc >> 3)) * 16) * 8 + (cc & 7);  // d1 = 16+cc
#pragma unroll
        for (int i = 0; i < 8; i++)
#pragma unroll
            for (int r = 0; r < 4; r++) {
                int pos = (m0 + i * 16 + quad * 4 + r) & 2047;
                int ob = (pos >> 4) * 1024 + (pos & 15) * 8;
                float s_, c_;
                __sincosf(pos * f0, &s_, &c_);
                float x1 = acc[i][0][r], x2 = acc[i][2][r];
                base[ob + o0]       = f2bf((x1 * c_ - x2 * s_) * scale);
                base[ob + o0 + 512] = f2bf((x2 * c_ + x1 * s_) * scale);
                __sincosf(pos * f1, &s_, &c_);
                x1 = acc[i][1][r]; x2 = acc[i][3][r];
                base[ob + o1]       = f2bf((x1 * c_ - x2 * s_) * scale);
                base[ob + o1 + 512] = f2bf((x2 * c_ + x1 * s_) * scale);
            }
    }
}

// GEMM2 split-K (2-phase dbuf): a2[4096][5120] @ W_out -> partials fp32
__global__ __launch_bounds__(256) void gemm2(const u16* __restrict__ a2,
        const u16* __restrict__ WoutT, float* __restrict__ p0, float* __restrict__ p1) {
    __shared__ u16 lds[2 * 8192];
    int bm = blockIdx.x * 128, bn = blockIdx.y * 128;
    int split = blockIdx.z;
    float* dst = split ? p1 : p0;
    f32x4 acc[4][4];
    gemm_core_128(a2 + split * 2560, VFF, WoutT + split * 2560, VFF, 2560,
                  bm, bn, acc, lds);
    const int tid = threadIdx.x, wid = tid >> 6, lane = tid & 63;
    const int quad = lane >> 4, cc = lane & 15;
    const int wm = (wid >> 1) * 64, wn = (wid & 1) * 64;
#pragma unroll
    for (int i = 0; i < 4; i++)
#pragma unroll
        for (int j = 0; j < 4; j++)
#pragma unroll
            for (int r = 0; r < 4; r++) {
                int m = bm + wm + i * 16 + quad * 4 + r;
                int n = bn + wn + j * 16 + cc;
                dst[(size_t)m * HIDDEN + n] = acc[i][j][r];
            }
}

__global__ __launch_bounds__(256) void reduce2(const float* __restrict__ p0,
        const float* __restrict__ p1, float* __restrict__ out) {
    int i = blockIdx.x * 256 + threadIdx.x;
    float4 a = ((const float4*)p0)[i];
    float4 b = ((const float4*)p1)[i];
    a.x += b.x; a.y += b.y; a.z += b.z; a.w += b.w;
    ((float4*)out)[i] = a;
}

// ------- Flash attention, causal, MFMA — FIXED-OFFSET softmax ---------------
// Q/K/V are pre-packed in MFMA fragment order (1KB blob per 16-row x 32-dim
// fragment, lane-major), so every fragment load is ONE contiguous 1KB wave
// load instead of a 16-segment row gather (R2 diagnosis: 256 divergent 64B
// transactions per chunk per wave -> MSHR/TA serialization, 73% stall).
__global__ __launch_bounds__(256) void attn_kernel(const u16* __restrict__ qk,
        const u16* __restrict__ vt, u16* __restrict__ a2) {
    const int id  = blockIdx.x;
    const int bh  = (id & 7) * 4 + ((id >> 3) & 3);
    const int bx  = id >> 5;
    const int tid = threadIdx.x;
    const int wid = tid >> 6;
    const int lane = tid & 63;
    const int quad = lane >> 4;
    const int cc = lane & 15;
    const int slot = wid >> 1;            // 0: tile bx, 1: tile 127-bx
    const int parity = wid & 1;
    const int tile = slot ? (127 - bx) : bx;
    const int q0 = tile * 16;

    const u16* Qp = qk + (size_t)bh * (SEQ * HEAD_DIM);
    const u16* Kp = qk + (size_t)(32 + bh) * (SEQ * HEAD_DIM);
    const u16* VP = vt + (size_t)bh * (HEAD_DIM * SEQ);

    __shared__ u16 Pbuf[4][16 * 72];      // per-wave P [q=16][key=64], stride 72
    __shared__ float obuf[2][64 * 17];    // merge: per-slot O^T (lane-major, pad 17)
    __shared__ float lbuf[2][16];         // merge: per-slot partial l per q
    u16* P = Pbuf[wid];

    const int bb = bh >> 4, hh = bh & 15;
    const int qcol = q0 + cc;

    // Q fragments from packed layout: one contiguous 1KB load per fragment
    bf16x8 qa0 = *(const bf16x8*)(Qp + (q0 >> 4) * 1024 + lane * 8);
    bf16x8 qa1 = *(const bf16x8*)(Qp + (q0 >> 4) * 1024 + 512 + lane * 8);

    float ps = 0.0f;                      // per-lane partial row-sum (this parity)
    f32x4 ot[4];                          // O^T: ot[mt][r] = O^T[d=mt*16+quad*4+r][q=cc]
#pragma unroll
    for (int mt = 0; mt < 4; mt++)
#pragma unroll
        for (int r = 0; r < 4; r++) ot[mt][r] = 0.0f;

    for (int kb = parity * 64; kb < q0 + 16; kb += 128) {
        const bool diag = (kb + 64 > q0);  // only the diagonal chunk needs masking
        // S^T = K Q^T - 32 (offset rides the accumulator init)
        f32x4 s[4];
        __builtin_amdgcn_s_setprio(1);
#pragma unroll
        for (int c = 0; c < 4; c++) {
            s[c][0] = -32.0f; s[c][1] = -32.0f; s[c][2] = -32.0f; s[c][3] = -32.0f;
            const u16* kblob = Kp + ((kb >> 4) + c) * 1024 + lane * 8;
            bf16x8 ka0 = *(const bf16x8*)(kblob);
            bf16x8 ka1 = *(const bf16x8*)(kblob + 512);
            s[c] = __builtin_amdgcn_mfma_f32_16x16x32_bf16(ka0, qa0, s[c], 0, 0, 0);
            s[c] = __builtin_amdgcn_mfma_f32_16x16x32_bf16(ka1, qa1, s[c], 0, 0, 0);
        }
        __builtin_amdgcn_s_setprio(0);
        // prefetch V^T for this chunk (overlaps the exp/stage phase)
        bf16x8 vf[2][4];
#pragma unroll
        for (int kc = 0; kc < 2; kc++)
#pragma unroll
            for (int mt = 0; mt < 4; mt++)
                vf[kc][mt] = *(const bf16x8*)(VP + ((kb >> 5) + kc) * 2048 + mt * 512 + lane * 8);
        // causal mask (diagonal chunk only; off-diag chunks are fully valid)
        if (diag) {
#pragma unroll
            for (int c = 0; c < 4; c++)
#pragma unroll
                for (int r = 0; r < 4; r++) {
                    int key = kb + c * 16 + quad * 4 + r;
                    s[c][r] = (key <= qcol) ? s[c][r] : -10000.0f;
                }
        }
        // P = exp2(s); local l accumulation (no cross-lane ops); cvt_pk pack
#pragma unroll
        for (int c = 0; c < 4; c++) {
            float p0v = exp2f(s[c][0]); ps += p0v;
            float p1v = exp2f(s[c][1]); ps += p1v;
            float p2v = exp2f(s[c][2]); ps += p2v;
            float p3v = exp2f(s[c][3]); ps += p3v;
            unsigned r0, r1;
            asm("v_cvt_pk_bf16_f32 %0, %1, %2" : "=v"(r0) : "v"(p0v), "v"(p1v));
            asm("v_cvt_pk_bf16_f32 %0, %1, %2" : "=v"(r1) : "v"(p2v), "v"(p3v));
            uint2 pk; pk.x = r0; pk.y = r1;
            *(uint2*)(P + cc * 72 + c * 16 + quad * 4) = pk;
        }
        asm volatile("s_waitcnt lgkmcnt(0)" ::: "memory");
        // O^T += V^T P^T
        __builtin_amdgcn_s_setprio(1);
#pragma unroll
        for (int kc = 0; kc < 2; kc++) {
            bf16x8 pb = *(const bf16x8*)(P + cc * 72 + kc * 32 + quad * 8);
#pragma unroll
            for (int mt = 0; mt < 4; mt++)
                ot[mt] = __builtin_amdgcn_mfma_f32_16x16x32_bf16(vf[kc][mt], pb, ot[mt], 0, 0, 0);
        }
        __builtin_amdgcn_s_setprio(0);
    }

    // ONE cross-lane l reduction (quads of same q-column)
    ps += __shfl_xor(ps, 16, 64);
    ps += __shfl_xor(ps, 32, 64);

    // ---- merge the two parity waves of each tile (plain add; no max) ----
    if (parity == 1) {
        if (quad == 0) lbuf[slot][cc] = ps;
        float* ob = obuf[slot] + lane * 17;
#pragma unroll
        for (int mt = 0; mt < 4; mt++)
#pragma unroll
            for (int r = 0; r < 4; r++) ob[mt * 4 + r] = ot[mt][r];
    }
    __syncthreads();
    if (parity == 0) {
        float l = ps + lbuf[slot][cc];
        float rl = 1.0f / l;
        const float* ob = obuf[slot] + lane * 17;
        u16* dst = a2 + ((size_t)(bb * SEQ + q0 + cc)) * VFF + hh * 64;
#pragma unroll
        for (int mt = 0; mt < 4; mt++) {
            ushort4 o;
            o.x = f2bf((ot[mt][0] + ob[mt * 4 + 0]) * rl);
            o.y = f2bf((ot[mt][1] + ob[mt * 4 + 1]) * rl);
            o.z = f2bf((ot[mt][2] + ob[mt * 4 + 2]) * rl);
            o.w = f2bf((ot[mt][3] + ob[mt * 4 + 3]) * rl);
            *(ushort4*)(dst + mt * 16 + quad * 4) = o;
        }
    }
}

extern "C" void kernel_launch(void* const* d_in, const int* in_sizes, int n_in,
                              void* d_out, int out_size, void* d_ws, size_t ws_size,
                              hipStream_t stream) {
    const float* x     = (const float*)d_in[0];
    const float* ln_w  = (const float*)d_in[1];
    const float* ln_b  = (const float*)d_in[2];
    const float* W_in  = (const float*)d_in[3];
    const float* W_out = (const float*)d_in[4];
    float* out = (float*)d_out;
    char* ws = (char*)d_ws;
    // Layout (peak 100663296 B):
    //   xn    @ 0         (8 MB)   dead after gemm1
    //   WinT  @ 8388608   (14 MB)  dead after gemm1
    //   qkb   @ 23068672  (16 MB)  gemm1 -> attn
    //   vtb   @ 39845888  (8 MB)   gemm1 -> attn
    //   WoutT @ 48234496  (10 MB)  -> gemm2
    //   a2    @ 58720256  (40 MB)  gemm1/attn -> gemm2
    //   p0    @ 0, p1 @ 16777216   gemm2 -> reduce2 (over dead xn/WinT/qkb)
    u16* xn    = (u16*)(ws);
    u16* WinT  = (u16*)(ws + 8388608);
    u16* qkb   = (u16*)(ws + 23068672);
    u16* vtb   = (u16*)(ws + 39845888);
    u16* WoutT = (u16*)(ws + 48234496);
    u16* a2    = (u16*)(ws + 58720256);
    float* p0  = (float*)(ws);
    float* p1  = (float*)(ws + 16777216);

    ln_kernel<<<dim3(MROWS), dim3(256), 0, stream>>>(x, ln_w, ln_b, xn);
    transpose_f2b<<<dim3(NQKVFF / 32, HIDDEN / 32), dim3(256), 0, stream>>>(W_in, WinT, HIDDEN, NQKVFF);
    transpose_f2b<<<dim3(HIDDEN / 32, VFF / 32), dim3(256), 0, stream>>>(W_out, WoutT, VFF, HIDDEN);
    gemm1<<<dim3(MROWS / 256, NQKVFF / 256), dim3(512), 0, stream>>>(xn, WinT, qkb, vtb, a2);
    attn_kernel<<<dim3(2048), dim3(256), 0, stream>>>(qkb, vtb, a2);
    gemm2<<<dim3(MROWS / 128, HIDDEN / 128, 2), dim3(256), 0, stream>>>(a2, WoutT, p0, p1);
    reduce2<<<dim3(MROWS * HIDDEN / 4 / 256), dim3(256), 0, stream>>>(p0, p1, out);
}